// Round 1
// baseline (1093.640 us; speedup 1.0000x reference)
//
#include <hip/hip_runtime.h>
#include <math.h>

#define SRATE   32000
#define NFFT    1024
#define HOP     320
#define NBINS   513
#define NMELS   128
#define NFRAMES 1001
#define NB      16
#define TLEN    320000
#define PCEN_EPS 1e-6f
#define LN_EPS   1e-6f
#define MAXW     64   // max nonzero band width per mel column (measured ~27)

// ---------------------------------------------------------------------------
// Pack the (mostly-zero, triangular) mel filterbank into per-mel bands.
// fb is [NBINS][NMELS] row-major. One thread per mel column.
__global__ void k_pack_fb(const float* __restrict__ fb, int* __restrict__ kmin,
                          int* __restrict__ klen, float* __restrict__ wv) {
    int m = threadIdx.x;
    if (m >= NMELS) return;
    int k0 = -1, k1 = -1;
    for (int k = 0; k < NBINS; ++k) {
        float w = fb[k * NMELS + m];
        if (w > 0.f) { if (k0 < 0) k0 = k; k1 = k; }
    }
    if (k0 < 0) { kmin[m] = 0; klen[m] = 0; return; }
    int L = k1 - k0 + 1;
    if (L > MAXW) L = MAXW;   // should never trigger
    kmin[m] = k0; klen[m] = L;
    for (int j = 0; j < L; ++j) wv[m * MAXW + j] = fb[(k0 + j) * NMELS + m];
}

// ---------------------------------------------------------------------------
// One block = one frame. Load+window, Stockham radix-2 FFT (natural order,
// no bit reversal), power spectrum, sparse mel projection. E -> out buffer.
__global__ __launch_bounds__(256) void k_melspec(
    const float* __restrict__ x,
    const int*   __restrict__ kmin,
    const int*   __restrict__ klen,
    const float* __restrict__ wv,
    const float* __restrict__ fb,     // dense fallback
    float* __restrict__ E,
    int usePacked)
{
    __shared__ float rA[NFFT], iA[NFFT], rB[NFFT], iB[NFFT];
    __shared__ float twr[512], twi[512];

    const int tid = threadIdx.x;
    const int f   = blockIdx.x;
    const int b   = f / NFRAMES;
    const int t   = f - b * NFRAMES;
    const float* xb = x + (size_t)b * TLEN;

    // twiddle table: tw[n] = exp(-i*pi*n/512), n = 0..511
    for (int n = tid; n < 512; n += 256) {
        float sn, cn;
        sincospif((float)n * (1.0f / 512.0f), &sn, &cn);
        twr[n] = cn; twi[n] = -sn;
    }

    // load with reflect padding, apply Hann window = sin^2(pi*i/N)
    const int base = t * HOP - (NFFT / 2);
    for (int i = tid; i < NFFT; i += 256) {
        int j = base + i;
        j = (j < 0) ? -j : ((j >= TLEN) ? (2 * TLEN - 2 - j) : j);
        float sp = sinpif((float)i * (1.0f / (float)NFFT));
        rA[i] = xb[j] * (sp * sp);
        iA[i] = 0.f;
    }
    __syncthreads();

    // Stockham radix-2, 10 stages, ping-pong rA/iA <-> rB/iB
    float *rs = rA, *is = iA, *rd = rB, *id = iB;
    for (int st = 0; st < 10; ++st) {
        const int m = 1 << st;
        for (int idx = tid; idx < 512; idx += 256) {
            const int j = idx >> st;
            const int k = idx & (m - 1);
            float ar = rs[idx],       ai = is[idx];
            float br = rs[idx + 512], bi = is[idx + 512];
            const int n = j << st;                // twiddle index
            float cw = twr[n], sw = twi[n];       // w = cw + i*sw
            const int o0 = k + (j << (st + 1));
            float sr_ = ar - br, si_ = ai - bi;
            rd[o0]     = ar + br;
            id[o0]     = ai + bi;
            rd[o0 + m] = sr_ * cw - si_ * sw;
            id[o0 + m] = sr_ * sw + si_ * cw;
        }
        __syncthreads();
        float* tp;
        tp = rs; rs = rd; rd = tp;
        tp = is; is = id; id = tp;
    }
    // after 10 swaps result is back in rA/iA; rd points at rB (free)

    // power spectrum -> rd[0..512]
    for (int k = tid; k < NBINS; k += 256) {
        float pr = rs[k], pi = is[k];
        rd[k] = pr * pr + pi * pi;
    }
    __syncthreads();

    // mel projection
    if (tid < NMELS) {
        const int m = tid;
        float acc = 0.f;
        if (usePacked) {
            const int k0 = kmin[m], L = klen[m];
            const float* w = wv + m * MAXW;
            for (int j = 0; j < L; ++j) acc += rd[k0 + j] * w[j];
        } else {
            for (int k = 0; k < NBINS; ++k) acc += rd[k] * fb[k * NMELS + m];
        }
        E[(size_t)f * NMELS + m] = acc;
    }
}

// ---------------------------------------------------------------------------
// Per-(b,mel) EMA scan + PCEN pointwise, in place on the E buffer.
// 2048 threads total; lane index = mel -> coalesced row accesses.
__global__ __launch_bounds__(256) void k_pcen(
    float* __restrict__ E,
    const float* __restrict__ p_ls, const float* __restrict__ p_la,
    const float* __restrict__ p_ld, const float* __restrict__ p_lr)
{
    const int gid = blockIdx.x * blockDim.x + threadIdx.x;  // 0..2047
    const int b = gid >> 7;
    const int m = gid & 127;

    const float s     = expf(p_ls[0]);
    const float alpha = expf(p_la[0]);
    const float delta = expf(p_ld[0]);
    const float r     = expf(p_lr[0]);
    const float dr    = powf(delta, r);
    const float a     = 1.f - s;

    float* col = E + (size_t)b * NFRAMES * NMELS + m;
    float M = col[0];
    for (int t = 0; t < NFRAMES; ++t) {
        float e = col[(size_t)t * NMELS];
        M = a * M + s * e;
        float den = __powf(PCEN_EPS + M, alpha);
        float p   = __powf(e / den + delta, r) - dr;
        col[(size_t)t * NMELS] = p;
    }
}

// ---------------------------------------------------------------------------
// Layernorm over the mel axis, one wave per row, in place.
__global__ __launch_bounds__(256) void k_ln(float* __restrict__ out) {
    const int wid  = threadIdx.x >> 6;
    const int lane = threadIdx.x & 63;
    const int row  = blockIdx.x * 4 + wid;   // 16016 rows = 4004 * 4 exactly
    float* p = out + (size_t)row * NMELS;
    float v0 = p[lane], v1 = p[lane + 64];
    float sum = v0 + v1;
    float sq  = v0 * v0 + v1 * v1;
    #pragma unroll
    for (int off = 32; off; off >>= 1) {
        sum += __shfl_xor(sum, off);
        sq  += __shfl_xor(sq,  off);
    }
    float mu  = sum * (1.f / 128.f);
    float var = sq * (1.f / 128.f) - mu * mu;
    float inv = rsqrtf(var + LN_EPS);
    p[lane]      = (v0 - mu) * inv;
    p[lane + 64] = (v1 - mu) * inv;
}

// ---------------------------------------------------------------------------
extern "C" void kernel_launch(void* const* d_in, const int* in_sizes, int n_in,
                              void* d_out, int out_size, void* d_ws, size_t ws_size,
                              hipStream_t stream) {
    const float* x   = (const float*)d_in[0];
    const float* fb  = (const float*)d_in[1];
    const float* lsp = (const float*)d_in[2];
    const float* lap = (const float*)d_in[3];
    const float* ldp = (const float*)d_in[4];
    const float* lrp = (const float*)d_in[5];
    float* out = (float*)d_out;

    const size_t need = (size_t)NMELS * 4 * 2 + (size_t)NMELS * MAXW * 4;
    int usePacked = (ws_size >= need) ? 1 : 0;

    int*   kmin = (int*)d_ws;
    int*   klen = kmin + NMELS;
    float* wv   = (float*)(klen + NMELS);

    if (usePacked)
        k_pack_fb<<<1, 128, 0, stream>>>(fb, kmin, klen, wv);

    k_melspec<<<NB * NFRAMES, 256, 0, stream>>>(x, kmin, klen, wv, fb, out, usePacked);
    k_pcen<<<(NB * NMELS) / 256, 256, 0, stream>>>(out, lsp, lap, ldp, lrp);
    k_ln<<<(NB * NFRAMES) / 4, 256, 0, stream>>>(out);
}

// Round 2
// 163.750 us; speedup vs baseline: 6.6787x; 6.6787x over previous
//
#include <hip/hip_runtime.h>
#include <math.h>

#define SRATE   32000
#define NFFT    1024
#define HOP     320
#define NBINS   513
#define NMELS   128
#define NFRAMES 1001
#define NB      16
#define TLEN    320000
#define PCEN_EPS 1e-6f
#define LN_EPS   1e-6f
#define MAXW     64   // max nonzero band width per mel column (measured ~27)

// ---- parallel-scan decomposition of the PCEN EMA ----
#define CL      16                    // chunk length (timesteps)
#define NCHUNK  63                    // ceil(1001/16): 62 full + last of 9

// ---------------------------------------------------------------------------
// Pack the (mostly-zero, triangular) mel filterbank into per-mel bands.
__global__ void k_pack_fb(const float* __restrict__ fb, int* __restrict__ kmin,
                          int* __restrict__ klen, float* __restrict__ wv) {
    int m = threadIdx.x;
    if (m >= NMELS) return;
    int k0 = -1, k1 = -1;
    for (int k = 0; k < NBINS; ++k) {
        float w = fb[k * NMELS + m];
        if (w > 0.f) { if (k0 < 0) k0 = k; k1 = k; }
    }
    if (k0 < 0) { kmin[m] = 0; klen[m] = 0; return; }
    int L = k1 - k0 + 1;
    if (L > MAXW) L = MAXW;
    kmin[m] = k0; klen[m] = L;
    for (int j = 0; j < L; ++j) wv[m * MAXW + j] = fb[(k0 + j) * NMELS + m];
}

// ---------------------------------------------------------------------------
// One block = one frame. Load+window, Stockham radix-2 FFT (natural order),
// power spectrum, sparse mel projection. E -> out buffer.
__global__ __launch_bounds__(256) void k_melspec(
    const float* __restrict__ x,
    const int*   __restrict__ kmin,
    const int*   __restrict__ klen,
    const float* __restrict__ wv,
    const float* __restrict__ fb,     // dense fallback
    float* __restrict__ E,
    int usePacked)
{
    __shared__ float rA[NFFT], iA[NFFT], rB[NFFT], iB[NFFT];
    __shared__ float twr[512], twi[512];

    const int tid = threadIdx.x;
    const int f   = blockIdx.x;
    const int b   = f / NFRAMES;
    const int t   = f - b * NFRAMES;
    const float* xb = x + (size_t)b * TLEN;

    for (int n = tid; n < 512; n += 256) {
        float sn, cn;
        sincospif((float)n * (1.0f / 512.0f), &sn, &cn);
        twr[n] = cn; twi[n] = -sn;
    }

    const int base = t * HOP - (NFFT / 2);
    for (int i = tid; i < NFFT; i += 256) {
        int j = base + i;
        j = (j < 0) ? -j : ((j >= TLEN) ? (2 * TLEN - 2 - j) : j);
        float sp = sinpif((float)i * (1.0f / (float)NFFT));
        rA[i] = xb[j] * (sp * sp);
        iA[i] = 0.f;
    }
    __syncthreads();

    float *rs = rA, *is = iA, *rd = rB, *id = iB;
    for (int st = 0; st < 10; ++st) {
        const int m = 1 << st;
        for (int idx = tid; idx < 512; idx += 256) {
            const int j = idx >> st;
            const int k = idx & (m - 1);
            float ar = rs[idx],       ai = is[idx];
            float br = rs[idx + 512], bi = is[idx + 512];
            const int n = j << st;
            float cw = twr[n], sw = twi[n];
            const int o0 = k + (j << (st + 1));
            float sr_ = ar - br, si_ = ai - bi;
            rd[o0]     = ar + br;
            id[o0]     = ai + bi;
            rd[o0 + m] = sr_ * cw - si_ * sw;
            id[o0 + m] = sr_ * sw + si_ * cw;
        }
        __syncthreads();
        float* tp;
        tp = rs; rs = rd; rd = tp;
        tp = is; is = id; id = tp;
    }

    for (int k = tid; k < NBINS; k += 256) {
        float pr = rs[k], pi = is[k];
        rd[k] = pr * pr + pi * pi;
    }
    __syncthreads();

    if (tid < NMELS) {
        const int m = tid;
        float acc = 0.f;
        if (usePacked) {
            const int k0 = kmin[m], L = klen[m];
            const float* w = wv + m * MAXW;
            for (int j = 0; j < L; ++j) acc += rd[k0 + j] * w[j];
        } else {
            for (int k = 0; k < NBINS; ++k) acc += rd[k] * fb[k * NMELS + m];
        }
        E[(size_t)f * NMELS + m] = acc;
    }
}

// ---------------------------------------------------------------------------
// PCEN phase 1: per-(b,chunk,m) thread computes the chunk's affine offset
//   B_c = s * sum_{j=0..L-1} a^{L-1-j} * e_{t0+j}     (multiplier = a^L)
__global__ __launch_bounds__(256) void k_pcen_chunk(
    const float* __restrict__ E, float* __restrict__ Bws,
    const float* __restrict__ p_ls)
{
    const int gid = blockIdx.x * blockDim.x + threadIdx.x;   // 0 .. 16*63*128-1
    const int m = gid & (NMELS - 1);
    const int c = (gid >> 7) % NCHUNK;
    const int b = gid / (NMELS * NCHUNK);

    const float s = expf(p_ls[0]);
    const float a = 1.f - s;

    const int t0 = c * CL;
    const int L  = (t0 + CL <= NFRAMES) ? CL : (NFRAMES - t0);
    const float* col = E + (size_t)b * NFRAMES * NMELS + m;

    float Bacc = 0.f;
    for (int j = 0; j < L; ++j)
        Bacc = a * Bacc + s * col[(size_t)(t0 + j) * NMELS];
    Bws[gid] = Bacc;
}

// ---------------------------------------------------------------------------
// PCEN phase 2: serial scan over the 63 chunk affines per column.
// Mws[(b,c,m)] = EMA carry entering chunk c.
__global__ __launch_bounds__(256) void k_pcen_scan(
    const float* __restrict__ E, const float* __restrict__ Bws,
    float* __restrict__ Mws, const float* __restrict__ p_ls)
{
    const int gid = blockIdx.x * blockDim.x + threadIdx.x;   // 0..2047
    const int m = gid & (NMELS - 1);
    const int b = gid >> 7;

    const float s   = expf(p_ls[0]);
    const float a   = 1.f - s;
    const float aCL = powf(a, (float)CL);

    float M = E[(size_t)b * NFRAMES * NMELS + m];   // carry init = E_0
    size_t base = (size_t)b * NCHUNK * NMELS + m;
    Mws[base] = M;
    for (int c = 0; c < NCHUNK - 1; ++c) {
        M = aCL * M + Bws[base + (size_t)c * NMELS];
        Mws[base + (size_t)(c + 1) * NMELS] = M;
    }
}

// ---------------------------------------------------------------------------
// PCEN phase 3: replay chunk from its carry, pointwise PCEN, in place.
__global__ __launch_bounds__(256) void k_pcen_apply(
    float* __restrict__ E, const float* __restrict__ Mws,
    const float* __restrict__ p_ls, const float* __restrict__ p_la,
    const float* __restrict__ p_ld, const float* __restrict__ p_lr)
{
    const int gid = blockIdx.x * blockDim.x + threadIdx.x;
    const int m = gid & (NMELS - 1);
    const int c = (gid >> 7) % NCHUNK;
    const int b = gid / (NMELS * NCHUNK);

    const float s     = expf(p_ls[0]);
    const float alpha = expf(p_la[0]);
    const float delta = expf(p_ld[0]);
    const float r     = expf(p_lr[0]);
    const float dr    = __powf(delta, r);
    const float a     = 1.f - s;

    const int t0 = c * CL;
    const int L  = (t0 + CL <= NFRAMES) ? CL : (NFRAMES - t0);
    float* col = E + (size_t)b * NFRAMES * NMELS + m;

    float M = Mws[((size_t)b * NCHUNK + c) * NMELS + m];
    for (int j = 0; j < L; ++j) {
        float e = col[(size_t)(t0 + j) * NMELS];
        M = a * M + s * e;
        float den = __powf(PCEN_EPS + M, alpha);
        float p   = __powf(e / den + delta, r) - dr;
        col[(size_t)(t0 + j) * NMELS] = p;
    }
}

// ---------------------------------------------------------------------------
// Fallback serial PCEN (used only if workspace is too small).
__global__ __launch_bounds__(256) void k_pcen_serial(
    float* __restrict__ E,
    const float* __restrict__ p_ls, const float* __restrict__ p_la,
    const float* __restrict__ p_ld, const float* __restrict__ p_lr)
{
    const int gid = blockIdx.x * blockDim.x + threadIdx.x;
    const int b = gid >> 7;
    const int m = gid & 127;

    const float s     = expf(p_ls[0]);
    const float alpha = expf(p_la[0]);
    const float delta = expf(p_ld[0]);
    const float r     = expf(p_lr[0]);
    const float dr    = powf(delta, r);
    const float a     = 1.f - s;

    float* col = E + (size_t)b * NFRAMES * NMELS + m;
    float M = col[0];
    for (int t = 0; t < NFRAMES; ++t) {
        float e = col[(size_t)t * NMELS];
        M = a * M + s * e;
        float den = __powf(PCEN_EPS + M, alpha);
        float p   = __powf(e / den + delta, r) - dr;
        col[(size_t)t * NMELS] = p;
    }
}

// ---------------------------------------------------------------------------
// Layernorm over the mel axis, one wave per row, in place.
__global__ __launch_bounds__(256) void k_ln(float* __restrict__ out) {
    const int wid  = threadIdx.x >> 6;
    const int lane = threadIdx.x & 63;
    const int row  = blockIdx.x * 4 + wid;   // 16016 rows = 4004 * 4 exactly
    float* p = out + (size_t)row * NMELS;
    float v0 = p[lane], v1 = p[lane + 64];
    float sum = v0 + v1;
    float sq  = v0 * v0 + v1 * v1;
    #pragma unroll
    for (int off = 32; off; off >>= 1) {
        sum += __shfl_xor(sum, off);
        sq  += __shfl_xor(sq,  off);
    }
    float mu  = sum * (1.f / 128.f);
    float var = sq * (1.f / 128.f) - mu * mu;
    float inv = rsqrtf(var + LN_EPS);
    p[lane]      = (v0 - mu) * inv;
    p[lane + 64] = (v1 - mu) * inv;
}

// ---------------------------------------------------------------------------
extern "C" void kernel_launch(void* const* d_in, const int* in_sizes, int n_in,
                              void* d_out, int out_size, void* d_ws, size_t ws_size,
                              hipStream_t stream) {
    const float* x   = (const float*)d_in[0];
    const float* fb  = (const float*)d_in[1];
    const float* lsp = (const float*)d_in[2];
    const float* lap = (const float*)d_in[3];
    const float* ldp = (const float*)d_in[4];
    const float* lrp = (const float*)d_in[5];
    float* out = (float*)d_out;

    const size_t packBytes = (size_t)NMELS * 4 * 2 + (size_t)NMELS * MAXW * 4;
    const size_t scanElems = (size_t)NB * NCHUNK * NMELS;        // 129024
    const size_t needPack  = packBytes;
    const size_t needScan  = packBytes + 2 * scanElems * 4;      // ~1.07 MB

    int usePacked = (ws_size >= needPack) ? 1 : 0;
    int useScan   = (ws_size >= needScan) ? 1 : 0;

    int*   kmin = (int*)d_ws;
    int*   klen = kmin + NMELS;
    float* wv   = (float*)(klen + NMELS);
    float* Bws  = wv + (size_t)NMELS * MAXW;
    float* Mws  = Bws + scanElems;

    if (usePacked)
        k_pack_fb<<<1, 128, 0, stream>>>(fb, kmin, klen, wv);

    k_melspec<<<NB * NFRAMES, 256, 0, stream>>>(x, kmin, klen, wv, fb, out, usePacked);

    if (useScan) {
        const int nThread = NB * NCHUNK * NMELS;                 // 129024
        k_pcen_chunk<<<nThread / 256, 256, 0, stream>>>(out, Bws, lsp);
        k_pcen_scan<<<(NB * NMELS) / 256, 256, 0, stream>>>(out, Bws, Mws, lsp);
        k_pcen_apply<<<nThread / 256, 256, 0, stream>>>(out, Mws, lsp, lap, ldp, lrp);
    } else {
        k_pcen_serial<<<(NB * NMELS) / 256, 256, 0, stream>>>(out, lsp, lap, ldp, lrp);
    }

    k_ln<<<(NB * NFRAMES) / 4, 256, 0, stream>>>(out);
}

// Round 3
// 142.380 us; speedup vs baseline: 7.6811x; 1.1501x over previous
//
#include <hip/hip_runtime.h>
#include <math.h>

#define SRATE   32000
#define NFFT    1024
#define HOP     320
#define NBINS   513
#define NMELS   128
#define NFRAMES 1001
#define NB      16
#define TLEN    320000
#define PCEN_EPS 1e-6f
#define LN_EPS   1e-6f
#define MAXW     64   // max nonzero band width per mel column (measured ~27)

// ---- parallel-scan decomposition of the PCEN EMA ----
#define CL      16                    // chunk length (timesteps)
#define NCHUNK  63                    // ceil(1001/16): 62 full + last of 9

// ---------------------------------------------------------------------------
// Once-per-launch setup: pack mel filterbank into per-mel bands + build
// window / twiddle tables in workspace.
__global__ void k_pack_fb(const float* __restrict__ fb, int* __restrict__ kmin,
                          int* __restrict__ klen, float* __restrict__ wv,
                          float* __restrict__ win, float* __restrict__ twr_g,
                          float* __restrict__ twi_g) {
    const int tid = threadIdx.x;   // 256
    if (tid < NMELS) {
        const int m = tid;
        int k0 = -1, k1 = -1;
        for (int k = 0; k < NBINS; ++k) {
            float w = fb[k * NMELS + m];
            if (w > 0.f) { if (k0 < 0) k0 = k; k1 = k; }
        }
        if (k0 < 0) { kmin[m] = 0; klen[m] = 0; }
        else {
            int L = k1 - k0 + 1;
            if (L > MAXW) L = MAXW;
            kmin[m] = k0; klen[m] = L;
            for (int j = 0; j < L; ++j) wv[m * MAXW + j] = fb[(k0 + j) * NMELS + m];
        }
    }
    for (int i = tid; i < NFFT; i += 256) {
        float sp = sinpif((float)i * (1.0f / (float)NFFT));
        win[i] = sp * sp;
    }
    for (int n = tid; n < 512; n += 256) {
        float sn, cn;
        sincospif((float)n * (1.0f / 512.0f), &sn, &cn);
        twr_g[n] = cn; twi_g[n] = -sn;
    }
}

// ---------------------------------------------------------------------------
// One block = TWO frames (two-for-one real FFT: frame 2g -> Re, 2g+1 -> Im).
// Load+window, Stockham radix-2 10-stage FFT, conjugate-symmetry untangle to
// two power spectra, sparse mel projection for both frames.
__global__ __launch_bounds__(256) void k_melspec(
    const float* __restrict__ x,
    const int*   __restrict__ kmin,
    const int*   __restrict__ klen,
    const float* __restrict__ wv,
    const float* __restrict__ fb,     // dense fallback
    const float* __restrict__ win_g,
    const float* __restrict__ twr_g,
    const float* __restrict__ twi_g,
    float* __restrict__ E,
    int usePacked)
{
    __shared__ float rA[NFFT], iA[NFFT], rB[NFFT], iB[NFFT];
    __shared__ float twr[512], twi[512];

    const int tid = threadIdx.x;
    const int g   = blockIdx.x;          // frame pair: f0 = 2g, f1 = 2g+1
    const int f0  = 2 * g, f1 = 2 * g + 1;
    const int b0  = f0 / NFRAMES, t0f = f0 - b0 * NFRAMES;
    const int b1  = f1 / NFRAMES, t1f = f1 - b1 * NFRAMES;
    const float* xb0 = x + (size_t)b0 * TLEN;
    const float* xb1 = x + (size_t)b1 * TLEN;

    if (usePacked) {
        for (int n = tid; n < 512; n += 256) { twr[n] = twr_g[n]; twi[n] = twi_g[n]; }
    } else {
        for (int n = tid; n < 512; n += 256) {
            float sn, cn;
            sincospif((float)n * (1.0f / 512.0f), &sn, &cn);
            twr[n] = cn; twi[n] = -sn;
        }
    }

    const int base0 = t0f * HOP - (NFFT / 2);
    const int base1 = t1f * HOP - (NFFT / 2);
    for (int i = tid; i < NFFT; i += 256) {
        int j0 = base0 + i;
        j0 = (j0 < 0) ? -j0 : ((j0 >= TLEN) ? (2 * TLEN - 2 - j0) : j0);
        int j1 = base1 + i;
        j1 = (j1 < 0) ? -j1 : ((j1 >= TLEN) ? (2 * TLEN - 2 - j1) : j1);
        float w;
        if (usePacked) w = win_g[i];
        else { float sp = sinpif((float)i * (1.0f / (float)NFFT)); w = sp * sp; }
        rA[i] = xb0[j0] * w;
        iA[i] = xb1[j1] * w;
    }
    __syncthreads();

    // Stockham radix-2, 10 stages, ping-pong rA/iA <-> rB/iB
    float *rs = rA, *is = iA, *rd = rB, *id = iB;
    for (int st = 0; st < 10; ++st) {
        const int m = 1 << st;
        for (int idx = tid; idx < 512; idx += 256) {
            const int j = idx >> st;
            const int k = idx & (m - 1);
            float ar = rs[idx],       ai = is[idx];
            float br = rs[idx + 512], bi = is[idx + 512];
            const int n = j << st;
            float cw = twr[n], sw = twi[n];
            const int o0 = k + (j << (st + 1));
            float sr_ = ar - br, si_ = ai - bi;
            rd[o0]     = ar + br;
            id[o0]     = ai + bi;
            rd[o0 + m] = sr_ * cw - si_ * sw;
            id[o0 + m] = sr_ * sw + si_ * cw;
        }
        __syncthreads();
        float* tp;
        tp = rs; rs = rd; rd = tp;
        tp = is; is = id; id = tp;
    }
    // 10 swaps -> result in rA/iA (rs/is); rB/iB (rd/id) free

    // Untangle: Z[k]=A+iB, Z[N-k]=C+iD
    //   power0[k] = ((A+C)^2 + (B-D)^2)/4   (frame f0)
    //   power1[k] = ((B+D)^2 + (C-A)^2)/4   (frame f1)
    for (int k = tid; k < NBINS; k += 256) {
        float A = rs[k], B = is[k];
        const int kr = (NFFT - k) & (NFFT - 1);
        float C = rs[kr], D = is[kr];
        float x1r = A + C, x1i = B - D;
        float x2r = B + D, x2i = C - A;
        rd[k] = 0.25f * (x1r * x1r + x1i * x1i);
        id[k] = 0.25f * (x2r * x2r + x2i * x2i);
    }
    __syncthreads();

    // mel projection: threads 0..127 -> frame f0 (rd), 128..255 -> f1 (id)
    {
        const int m    = tid & 127;
        const int half = tid >> 7;
        const float* spec = half ? id : rd;
        const int fo = 2 * g + half;
        float acc = 0.f;
        if (usePacked) {
            const int k0 = kmin[m], L = klen[m];
            const float* w = wv + m * MAXW;
            for (int j = 0; j < L; ++j) acc += spec[k0 + j] * w[j];
        } else {
            for (int k = 0; k < NBINS; ++k) acc += spec[k] * fb[k * NMELS + m];
        }
        E[(size_t)fo * NMELS + m] = acc;
    }
}

// ---------------------------------------------------------------------------
// PCEN phase 1: per-(b,chunk,m) thread computes the chunk's affine offset
//   B_c = s * sum_{j} a^{L-1-j} * e_{t0+j}
__global__ __launch_bounds__(256) void k_pcen_chunk(
    const float* __restrict__ E, float* __restrict__ Bws,
    const float* __restrict__ p_ls)
{
    const int gid = blockIdx.x * blockDim.x + threadIdx.x;
    const int m = gid & (NMELS - 1);
    const int c = (gid >> 7) % NCHUNK;
    const int b = gid / (NMELS * NCHUNK);

    const float s = expf(p_ls[0]);
    const float a = 1.f - s;

    const int t0 = c * CL;
    const int L  = (t0 + CL <= NFRAMES) ? CL : (NFRAMES - t0);
    const float* col = E + (size_t)b * NFRAMES * NMELS + m;

    float Bacc = 0.f;
    for (int j = 0; j < L; ++j)
        Bacc = a * Bacc + s * col[(size_t)(t0 + j) * NMELS];
    Bws[gid] = Bacc;
}

// ---------------------------------------------------------------------------
// PCEN phase 2: serial scan over the 63 chunk affines per column.
__global__ __launch_bounds__(256) void k_pcen_scan(
    const float* __restrict__ E, const float* __restrict__ Bws,
    float* __restrict__ Mws, const float* __restrict__ p_ls)
{
    const int gid = blockIdx.x * blockDim.x + threadIdx.x;   // 0..2047
    const int m = gid & (NMELS - 1);
    const int b = gid >> 7;

    const float s   = expf(p_ls[0]);
    const float a   = 1.f - s;
    const float aCL = powf(a, (float)CL);

    float M = E[(size_t)b * NFRAMES * NMELS + m];   // carry init = E_0
    size_t base = (size_t)b * NCHUNK * NMELS + m;
    Mws[base] = M;
    for (int c = 0; c < NCHUNK - 1; ++c) {
        M = aCL * M + Bws[base + (size_t)c * NMELS];
        Mws[base + (size_t)(c + 1) * NMELS] = M;
    }
}

// ---------------------------------------------------------------------------
// PCEN phase 3 fused with layernorm. One block = (b, chunk-pair):
// threads 0..127 replay chunk 2*cp, threads 128..255 replay chunk 2*cp+1,
// pcen values staged in LDS, then 4 waves layernorm the 32 frames in place.
__global__ __launch_bounds__(256) void k_pcen_ln(
    float* __restrict__ E, const float* __restrict__ Mws,
    const float* __restrict__ p_ls, const float* __restrict__ p_la,
    const float* __restrict__ p_ld, const float* __restrict__ p_lr)
{
    __shared__ float sm[2 * CL][NMELS];   // 16 KB

    const int tid  = threadIdx.x;
    const int half = tid >> 7;
    const int m    = tid & 127;
    const int b    = blockIdx.x >> 5;     // 32 chunk-pairs per batch
    const int cp   = blockIdx.x & 31;
    const int c    = cp * 2 + half;

    const float s     = expf(p_ls[0]);
    const float alpha = expf(p_la[0]);
    const float delta = expf(p_ld[0]);
    const float r     = expf(p_lr[0]);
    const float dr    = __powf(delta, r);
    const float a     = 1.f - s;

    if (c < NCHUNK) {
        const int t0 = c * CL;
        const int L  = (t0 + CL <= NFRAMES) ? CL : (NFRAMES - t0);
        const float* col = E + ((size_t)b * NFRAMES + t0) * NMELS + m;
        float M = Mws[((size_t)b * NCHUNK + c) * NMELS + m];
        for (int j = 0; j < L; ++j) {
            float e = col[(size_t)j * NMELS];
            M = a * M + s * e;
            float den = __powf(PCEN_EPS + M, alpha);
            sm[half * CL + j][m] = __powf(e / den + delta, r) - dr;
        }
    }
    __syncthreads();

    // layernorm: 4 waves cover the 32 staged frames
    const int wid  = tid >> 6;
    const int lane = tid & 63;
    for (int row = wid; row < 2 * CL; row += 4) {
        const int cc = cp * 2 + (row >> 4);
        if (cc >= NCHUNK) continue;
        const int j   = row & (CL - 1);
        const int tt0 = cc * CL;
        const int LL  = (tt0 + CL <= NFRAMES) ? CL : (NFRAMES - tt0);
        if (j >= LL) continue;
        float v0 = sm[row][lane], v1 = sm[row][lane + 64];
        float sum = v0 + v1;
        float sq  = v0 * v0 + v1 * v1;
        #pragma unroll
        for (int off = 32; off; off >>= 1) {
            sum += __shfl_xor(sum, off);
            sq  += __shfl_xor(sq,  off);
        }
        float mu  = sum * (1.f / 128.f);
        float var = sq * (1.f / 128.f) - mu * mu;
        float inv = rsqrtf(var + LN_EPS);
        float* p = E + ((size_t)b * NFRAMES + tt0 + j) * NMELS;
        p[lane]      = (v0 - mu) * inv;
        p[lane + 64] = (v1 - mu) * inv;
    }
}

// ---------------------------------------------------------------------------
// Fallback serial PCEN (used only if workspace is too small).
__global__ __launch_bounds__(256) void k_pcen_serial(
    float* __restrict__ E,
    const float* __restrict__ p_ls, const float* __restrict__ p_la,
    const float* __restrict__ p_ld, const float* __restrict__ p_lr)
{
    const int gid = blockIdx.x * blockDim.x + threadIdx.x;
    const int b = gid >> 7;
    const int m = gid & 127;

    const float s     = expf(p_ls[0]);
    const float alpha = expf(p_la[0]);
    const float delta = expf(p_ld[0]);
    const float r     = expf(p_lr[0]);
    const float dr    = powf(delta, r);
    const float a     = 1.f - s;

    float* col = E + (size_t)b * NFRAMES * NMELS + m;
    float M = col[0];
    for (int t = 0; t < NFRAMES; ++t) {
        float e = col[(size_t)t * NMELS];
        M = a * M + s * e;
        float den = __powf(PCEN_EPS + M, alpha);
        float p   = __powf(e / den + delta, r) - dr;
        col[(size_t)t * NMELS] = p;
    }
}

// ---------------------------------------------------------------------------
// Standalone layernorm (fallback path only).
__global__ __launch_bounds__(256) void k_ln(float* __restrict__ out) {
    const int wid  = threadIdx.x >> 6;
    const int lane = threadIdx.x & 63;
    const int row  = blockIdx.x * 4 + wid;
    float* p = out + (size_t)row * NMELS;
    float v0 = p[lane], v1 = p[lane + 64];
    float sum = v0 + v1;
    float sq  = v0 * v0 + v1 * v1;
    #pragma unroll
    for (int off = 32; off; off >>= 1) {
        sum += __shfl_xor(sum, off);
        sq  += __shfl_xor(sq,  off);
    }
    float mu  = sum * (1.f / 128.f);
    float var = sq * (1.f / 128.f) - mu * mu;
    float inv = rsqrtf(var + LN_EPS);
    p[lane]      = (v0 - mu) * inv;
    p[lane + 64] = (v1 - mu) * inv;
}

// ---------------------------------------------------------------------------
extern "C" void kernel_launch(void* const* d_in, const int* in_sizes, int n_in,
                              void* d_out, int out_size, void* d_ws, size_t ws_size,
                              hipStream_t stream) {
    const float* x   = (const float*)d_in[0];
    const float* fb  = (const float*)d_in[1];
    const float* lsp = (const float*)d_in[2];
    const float* lap = (const float*)d_in[3];
    const float* ldp = (const float*)d_in[4];
    const float* lrp = (const float*)d_in[5];
    float* out = (float*)d_out;

    const size_t packElems = (size_t)NMELS * 2            // kmin,klen (as 4B)
                           + (size_t)NMELS * MAXW         // wv
                           + NFFT + 512 + 512;            // win, twr, twi
    const size_t scanElems = (size_t)NB * NCHUNK * NMELS; // 129024
    const size_t needPack  = packElems * 4;
    const size_t needScan  = needPack + 2 * scanElems * 4;

    int usePacked = (ws_size >= needPack) ? 1 : 0;
    int useScan   = (ws_size >= needScan) ? 1 : 0;

    int*   kmin = (int*)d_ws;
    int*   klen = kmin + NMELS;
    float* wv   = (float*)(klen + NMELS);
    float* win  = wv + (size_t)NMELS * MAXW;
    float* twr  = win + NFFT;
    float* twi  = twr + 512;
    float* Bws  = twi + 512;
    float* Mws  = Bws + scanElems;

    if (usePacked)
        k_pack_fb<<<1, 256, 0, stream>>>(fb, kmin, klen, wv, win, twr, twi);

    k_melspec<<<NB * NFRAMES / 2, 256, 0, stream>>>(
        x, kmin, klen, wv, fb, win, twr, twi, out, usePacked);

    if (useScan) {
        const int nThread = NB * NCHUNK * NMELS;                 // 129024
        k_pcen_chunk<<<nThread / 256, 256, 0, stream>>>(out, Bws, lsp);
        k_pcen_scan<<<(NB * NMELS) / 256, 256, 0, stream>>>(out, Bws, Mws, lsp);
        k_pcen_ln<<<NB * 32, 256, 0, stream>>>(out, Mws, lsp, lap, ldp, lrp);
    } else {
        k_pcen_serial<<<(NB * NMELS) / 256, 256, 0, stream>>>(out, lsp, lap, ldp, lrp);
        k_ln<<<(NB * NFRAMES) / 4, 256, 0, stream>>>(out);
    }
}

// Round 4
// 110.146 us; speedup vs baseline: 9.9290x; 1.2927x over previous
//
#include <hip/hip_runtime.h>
#include <math.h>

#define SRATE   32000
#define NFFT    1024
#define HOP     320
#define NBINS   513
#define NMELS   128
#define NFRAMES 1001
#define NB      16
#define TLEN    320000
#define PCEN_EPS 1e-6f
#define LN_EPS   1e-6f
#define MAXW     64   // max nonzero band width per mel column (measured ~27)

// ---- parallel-scan decomposition of the PCEN EMA ----
#define CL      16                    // chunk length (timesteps)
#define NCHUNK  63                    // ceil(1001/16): 62 full + last of 9

// ---------------------------------------------------------------------------
// Parallel prep: one block per mel packs the filterbank band; 6 extra blocks
// build the window and twiddle tables.
__global__ __launch_bounds__(256) void k_prep(
    const float* __restrict__ fb, int* __restrict__ kmin, int* __restrict__ klen,
    float* __restrict__ wv, float* __restrict__ win,
    float* __restrict__ twr_g, float* __restrict__ twi_g)
{
    const int blk = blockIdx.x;
    const int tid = threadIdx.x;
    if (blk < NMELS) {
        const int m = blk;
        __shared__ int smin[4], smax[4];
        int lmin = 1 << 30, lmax = -1;
        for (int k = tid; k < NBINS; k += 256) {
            if (fb[k * NMELS + m] > 0.f) {
                if (k < lmin) lmin = k;
                if (k > lmax) lmax = k;
            }
        }
        #pragma unroll
        for (int off = 32; off; off >>= 1) {
            int om = __shfl_xor(lmin, off); if (om < lmin) lmin = om;
            int ox = __shfl_xor(lmax, off); if (ox > lmax) lmax = ox;
        }
        if ((tid & 63) == 0) { smin[tid >> 6] = lmin; smax[tid >> 6] = lmax; }
        __syncthreads();
        int k0 = min(min(smin[0], smin[1]), min(smin[2], smin[3]));
        int k1 = max(max(smax[0], smax[1]), max(smax[2], smax[3]));
        int L  = (k1 < 0) ? 0 : min(k1 - k0 + 1, MAXW);
        if (tid == 0) { kmin[m] = (k1 < 0) ? 0 : k0; klen[m] = L; }
        if (tid < L) wv[m * MAXW + tid] = fb[(k0 + tid) * NMELS + m];
    } else {
        const int i = (blk - NMELS) * 256 + tid;   // 0..1535
        if (i < NFFT) {
            float sp = sinpif((float)i * (1.0f / (float)NFFT));
            win[i] = sp * sp;
        } else if (i < NFFT + 512) {
            int n = i - NFFT;
            float sn, cn;
            sincospif((float)n * (1.0f / 512.0f), &sn, &cn);
            twr_g[n] = cn; twi_g[n] = -sn;
        }
    }
}

// ---------------------------------------------------------------------------
// One block = TWO frames (two-for-one real FFT). Radix-4 Stockham, 5 stages:
//   dst[k + 4jm + p*m] = (DFT4_p over q of src[j*m+k+q*256]) * W^{p*j*m},
//   W = exp(-2*pi*i/1024).  Natural-order output, no bit reversal.
__global__ __launch_bounds__(256) void k_melspec(
    const float* __restrict__ x,
    const int*   __restrict__ kmin,
    const int*   __restrict__ klen,
    const float* __restrict__ wv,
    const float* __restrict__ fb,     // dense fallback
    const float* __restrict__ win_g,
    const float* __restrict__ twr_g,
    const float* __restrict__ twi_g,
    float* __restrict__ E,
    int usePacked)
{
    __shared__ float rA[NFFT], iA[NFFT], rB[NFFT], iB[NFFT];
    __shared__ float twr[256], twi[256];

    const int tid = threadIdx.x;
    const int g   = blockIdx.x;          // frame pair: f0 = 2g, f1 = 2g+1
    const int f0  = 2 * g, f1 = 2 * g + 1;
    const int b0  = f0 / NFRAMES, t0f = f0 - b0 * NFRAMES;
    const int b1  = f1 / NFRAMES, t1f = f1 - b1 * NFRAMES;
    const float* xb0 = x + (size_t)b0 * TLEN;
    const float* xb1 = x + (size_t)b1 * TLEN;

    if (usePacked) {
        twr[tid] = twr_g[tid]; twi[tid] = twi_g[tid];
    } else {
        float sn, cn;
        sincospif((float)tid * (1.0f / 512.0f), &sn, &cn);
        twr[tid] = cn; twi[tid] = -sn;
    }

    const int base0 = t0f * HOP - (NFFT / 2);
    const int base1 = t1f * HOP - (NFFT / 2);
    for (int i = tid; i < NFFT; i += 256) {
        int j0 = base0 + i;
        j0 = (j0 < 0) ? -j0 : ((j0 >= TLEN) ? (2 * TLEN - 2 - j0) : j0);
        int j1 = base1 + i;
        j1 = (j1 < 0) ? -j1 : ((j1 >= TLEN) ? (2 * TLEN - 2 - j1) : j1);
        float w;
        if (usePacked) w = win_g[i];
        else { float sp = sinpif((float)i * (1.0f / (float)NFFT)); w = sp * sp; }
        rA[i] = xb0[j0] * w;
        iA[i] = xb1[j1] * w;
    }
    __syncthreads();

    float *rs = rA, *is = iA, *rd = rB, *id = iB;
    #pragma unroll
    for (int st = 0; st < 5; ++st) {
        const int mm = 1 << (2 * st);
        const int n  = tid & ~(mm - 1);            // j*m  (twiddle exponent)
        const int o  = (n << 2) | (tid & (mm - 1)); // k + 4*j*m
        float a0r = rs[tid],       a0i = is[tid];
        float a1r = rs[tid + 256], a1i = is[tid + 256];
        float a2r = rs[tid + 512], a2i = is[tid + 512];
        float a3r = rs[tid + 768], a3i = is[tid + 768];
        float c1 = twr[n], s1 = twi[n];
        float c2 = c1 * c1 - s1 * s1, s2 = 2.f * c1 * s1;
        float c3 = c1 * c2 - s1 * s2, s3 = c1 * s2 + s1 * c2;
        float t0r = a0r + a2r, t0i = a0i + a2i;
        float t1r = a0r - a2r, t1i = a0i - a2i;
        float t2r = a1r + a3r, t2i = a1i + a3i;
        float t3r = a1i - a3i, t3i = a3r - a1r;    // -i*(a1-a3)
        float y1r = t1r + t3r, y1i = t1i + t3i;
        float y2r = t0r - t2r, y2i = t0i - t2i;
        float y3r = t1r - t3r, y3i = t1i - t3i;
        rd[o]          = t0r + t2r;          id[o]          = t0i + t2i;
        rd[o + mm]     = y1r * c1 - y1i * s1; id[o + mm]     = y1r * s1 + y1i * c1;
        rd[o + 2 * mm] = y2r * c2 - y2i * s2; id[o + 2 * mm] = y2r * s2 + y2i * c2;
        rd[o + 3 * mm] = y3r * c3 - y3i * s3; id[o + 3 * mm] = y3r * s3 + y3i * c3;
        __syncthreads();
        float* tp;
        tp = rs; rs = rd; rd = tp;
        tp = is; is = id; id = tp;
    }
    // 5 swaps: result in rs/is (=rB/iB), scratch rd/id (=rA/iA)

    // Untangle: Z[k]=A+iB, Z[N-k]=C+iD
    for (int k = tid; k < NBINS; k += 256) {
        float A = rs[k], B = is[k];
        const int kr = (NFFT - k) & (NFFT - 1);
        float C = rs[kr], D = is[kr];
        float x1r = A + C, x1i = B - D;
        float x2r = B + D, x2i = C - A;
        rd[k] = 0.25f * (x1r * x1r + x1i * x1i);
        id[k] = 0.25f * (x2r * x2r + x2i * x2i);
    }
    __syncthreads();

    // mel projection: threads 0..127 -> frame f0 (rd), 128..255 -> f1 (id)
    {
        const int m    = tid & 127;
        const int half = tid >> 7;
        const float* spec = half ? id : rd;
        const int fo = 2 * g + half;
        float acc = 0.f;
        if (usePacked) {
            const int k0 = kmin[m], L = klen[m];
            const float* w = wv + m * MAXW;
            for (int j = 0; j < L; ++j) acc += spec[k0 + j] * w[j];
        } else {
            for (int k = 0; k < NBINS; ++k) acc += spec[k] * fb[k * NMELS + m];
        }
        E[(size_t)fo * NMELS + m] = acc;
    }
}

// ---------------------------------------------------------------------------
// PCEN phase 1: per-(b,chunk,m) affine offset B_c = s * sum_j a^{L-1-j} e_j.
// Also snapshots E[:,0,:] (needed by phase 2 after E starts being overwritten).
__global__ __launch_bounds__(256) void k_pcen_chunk(
    const float* __restrict__ E, float* __restrict__ Bws,
    float* __restrict__ E0ws, const float* __restrict__ p_ls)
{
    const int gid = blockIdx.x * blockDim.x + threadIdx.x;
    const int m = gid & (NMELS - 1);
    const int c = (gid >> 7) % NCHUNK;
    const int b = gid / (NMELS * NCHUNK);

    const float s = expf(p_ls[0]);
    const float a = 1.f - s;

    const int t0 = c * CL;
    const int L  = (t0 + CL <= NFRAMES) ? CL : (NFRAMES - t0);
    const float* col = E + (size_t)b * NFRAMES * NMELS + m;

    if (c == 0) E0ws[b * NMELS + m] = col[0];

    float Bacc = 0.f;
    for (int j = 0; j < L; ++j)
        Bacc = a * Bacc + s * col[(size_t)(t0 + j) * NMELS];
    Bws[gid] = Bacc;
}

// ---------------------------------------------------------------------------
// PCEN phase 2 fused with layernorm. One block = (b, chunk-pair). Each half
// recomputes its chunk's EMA carry by scanning Bws (<=62 coalesced L2 loads),
// replays the chunk with pointwise PCEN into LDS, then 4 waves layernorm the
// 32 frames in place.
__global__ __launch_bounds__(256) void k_pcen_ln(
    float* __restrict__ E, const float* __restrict__ Bws,
    const float* __restrict__ E0ws,
    const float* __restrict__ p_ls, const float* __restrict__ p_la,
    const float* __restrict__ p_ld, const float* __restrict__ p_lr)
{
    __shared__ float sm[2 * CL][NMELS];   // 16 KB

    const int tid  = threadIdx.x;
    const int half = tid >> 7;
    const int m    = tid & 127;
    const int b    = blockIdx.x >> 5;     // 32 chunk-pairs per batch
    const int cp   = blockIdx.x & 31;
    const int c    = cp * 2 + half;

    const float s     = expf(p_ls[0]);
    const float alpha = expf(p_la[0]);
    const float delta = expf(p_ld[0]);
    const float r     = expf(p_lr[0]);
    const float dr    = __powf(delta, r);
    const float a     = 1.f - s;
    const float a2 = a * a, a4 = a2 * a2, a8 = a4 * a4;
    const float a16 = a8 * a8;            // a^CL, all scanned chunks are full

    if (c < NCHUNK) {
        // self-scan: carry entering chunk c
        float M = E0ws[b * NMELS + m];
        const float* Bcol = Bws + (size_t)b * NCHUNK * NMELS + m;
        for (int cc = 0; cc < c; ++cc)
            M = a16 * M + Bcol[(size_t)cc * NMELS];

        const int t0 = c * CL;
        const int L  = (t0 + CL <= NFRAMES) ? CL : (NFRAMES - t0);
        const float* col = E + ((size_t)b * NFRAMES + t0) * NMELS + m;
        for (int j = 0; j < L; ++j) {
            float e = col[(size_t)j * NMELS];
            M = a * M + s * e;
            float den = __powf(PCEN_EPS + M, alpha);
            sm[half * CL + j][m] = __powf(e / den + delta, r) - dr;
        }
    }
    __syncthreads();

    // layernorm: 4 waves cover the 32 staged frames
    const int wid  = tid >> 6;
    const int lane = tid & 63;
    for (int row = wid; row < 2 * CL; row += 4) {
        const int cc = cp * 2 + (row >> 4);
        if (cc >= NCHUNK) continue;
        const int j   = row & (CL - 1);
        const int tt0 = cc * CL;
        const int LL  = (tt0 + CL <= NFRAMES) ? CL : (NFRAMES - tt0);
        if (j >= LL) continue;
        float v0 = sm[row][lane], v1 = sm[row][lane + 64];
        float sum = v0 + v1;
        float sq  = v0 * v0 + v1 * v1;
        #pragma unroll
        for (int off = 32; off; off >>= 1) {
            sum += __shfl_xor(sum, off);
            sq  += __shfl_xor(sq,  off);
        }
        float mu  = sum * (1.f / 128.f);
        float var = sq * (1.f / 128.f) - mu * mu;
        float inv = rsqrtf(var + LN_EPS);
        float* p = E + ((size_t)b * NFRAMES + tt0 + j) * NMELS;
        p[lane]      = (v0 - mu) * inv;
        p[lane + 64] = (v1 - mu) * inv;
    }
}

// ---------------------------------------------------------------------------
// Fallback serial PCEN + LN (used only if workspace is too small).
__global__ __launch_bounds__(256) void k_pcen_serial(
    float* __restrict__ E,
    const float* __restrict__ p_ls, const float* __restrict__ p_la,
    const float* __restrict__ p_ld, const float* __restrict__ p_lr)
{
    const int gid = blockIdx.x * blockDim.x + threadIdx.x;
    const int b = gid >> 7;
    const int m = gid & 127;

    const float s     = expf(p_ls[0]);
    const float alpha = expf(p_la[0]);
    const float delta = expf(p_ld[0]);
    const float r     = expf(p_lr[0]);
    const float dr    = powf(delta, r);
    const float a     = 1.f - s;

    float* col = E + (size_t)b * NFRAMES * NMELS + m;
    float M = col[0];
    for (int t = 0; t < NFRAMES; ++t) {
        float e = col[(size_t)t * NMELS];
        M = a * M + s * e;
        float den = __powf(PCEN_EPS + M, alpha);
        float p   = __powf(e / den + delta, r) - dr;
        col[(size_t)t * NMELS] = p;
    }
}

__global__ __launch_bounds__(256) void k_ln(float* __restrict__ out) {
    const int wid  = threadIdx.x >> 6;
    const int lane = threadIdx.x & 63;
    const int row  = blockIdx.x * 4 + wid;
    float* p = out + (size_t)row * NMELS;
    float v0 = p[lane], v1 = p[lane + 64];
    float sum = v0 + v1;
    float sq  = v0 * v0 + v1 * v1;
    #pragma unroll
    for (int off = 32; off; off >>= 1) {
        sum += __shfl_xor(sum, off);
        sq  += __shfl_xor(sq,  off);
    }
    float mu  = sum * (1.f / 128.f);
    float var = sq * (1.f / 128.f) - mu * mu;
    float inv = rsqrtf(var + LN_EPS);
    p[lane]      = (v0 - mu) * inv;
    p[lane + 64] = (v1 - mu) * inv;
}

// ---------------------------------------------------------------------------
extern "C" void kernel_launch(void* const* d_in, const int* in_sizes, int n_in,
                              void* d_out, int out_size, void* d_ws, size_t ws_size,
                              hipStream_t stream) {
    const float* x   = (const float*)d_in[0];
    const float* fb  = (const float*)d_in[1];
    const float* lsp = (const float*)d_in[2];
    const float* lap = (const float*)d_in[3];
    const float* ldp = (const float*)d_in[4];
    const float* lrp = (const float*)d_in[5];
    float* out = (float*)d_out;

    const size_t packElems = (size_t)NMELS * 2            // kmin, klen
                           + (size_t)NMELS * MAXW         // wv
                           + NFFT + 512 + 512;            // win, twr, twi
    const size_t scanElems = (size_t)NB * NCHUNK * NMELS; // 129024
    const size_t needPack  = packElems * 4;
    const size_t needScan  = (packElems + scanElems + (size_t)NB * NMELS) * 4;

    int usePacked = (ws_size >= needPack) ? 1 : 0;
    int useScan   = (ws_size >= needScan) ? 1 : 0;

    int*   kmin = (int*)d_ws;
    int*   klen = kmin + NMELS;
    float* wv   = (float*)(klen + NMELS);
    float* win  = wv + (size_t)NMELS * MAXW;
    float* twr  = win + NFFT;
    float* twi  = twr + 512;
    float* Bws  = twi + 512;
    float* E0ws = Bws + scanElems;

    if (usePacked)
        k_prep<<<NMELS + 6, 256, 0, stream>>>(fb, kmin, klen, wv, win, twr, twi);

    k_melspec<<<NB * NFRAMES / 2, 256, 0, stream>>>(
        x, kmin, klen, wv, fb, win, twr, twi, out, usePacked);

    if (useScan) {
        const int nThread = NB * NCHUNK * NMELS;                 // 129024
        k_pcen_chunk<<<nThread / 256, 256, 0, stream>>>(out, Bws, E0ws, lsp);
        k_pcen_ln<<<NB * 32, 256, 0, stream>>>(out, Bws, E0ws, lsp, lap, ldp, lrp);
    } else {
        k_pcen_serial<<<(NB * NMELS) / 256, 256, 0, stream>>>(out, lsp, lap, ldp, lrp);
        k_ln<<<(NB * NFRAMES) / 4, 256, 0, stream>>>(out);
    }
}